// Round 5
// baseline (363.441 us; speedup 1.0000x reference)
//
#include <hip/hip_runtime.h>
#include <math.h>

#define SEQ 2048
#define NHEAD 8
#define HDIM 64
#define BATCH 2

typedef __attribute__((ext_vector_type(8))) short short8;
typedef __attribute__((ext_vector_type(4))) float f32x4;

__device__ __forceinline__ ushort f2bf(float f) {
    union { float f; unsigned u; } v; v.f = f;
    unsigned r = v.u + 0x7FFFu + ((v.u >> 16) & 1u);   // RNE
    return (ushort)(r >> 16);
}

__device__ __forceinline__ f32x4 mfma16(short8 a, short8 b, f32x4 c) {
    return __builtin_amdgcn_mfma_f32_16x16x32_bf16(a, b, c, 0, 0, 0);
}

// global->LDS DMA, 16B per lane; ldsp must be wave-uniform (lane i lands at
// ldsp + i*16).
__device__ __forceinline__ void gld16(const void* g, void* l) {
    __builtin_amdgcn_global_load_lds(
        (const __attribute__((address_space(1))) unsigned int*)g,
        (__attribute__((address_space(3))) unsigned int*)l, 16, 0, 0);
}

// ------- fused prep: pack x + transpose both weights + RoPE table --------
__global__ __launch_bounds__(256)
void prep(const float* __restrict__ x, const float* __restrict__ w_qkv,
          const float* __restrict__ w_out, ushort* __restrict__ xb,
          ushort* __restrict__ wqkvT, ushort* __restrict__ woutT,
          float2* __restrict__ rope_tbl)
{
    __shared__ ushort tile[64][66];
    const int blk = blockIdx.x, t = threadIdx.x;
    if (blk >= 1280) {                      // RoPE cos/sin table [2048][32]
        const int idx = (blk - 1280) * 256 + t;      // 0..4095
        const int n = idx >> 1, fbase = (idx & 1) * 16;
#pragma unroll
        for (int f = 0; f < 16; ++f) {
            const float inv = __expf(-(float)(fbase + f) * (9.2103403719761836f / 32.0f));
            float sn, cs;
            __sincosf((float)n * inv, &sn, &cs);
            rope_tbl[(size_t)n * 32 + fbase + f] = make_float2(cs, sn);
        }
        return;
    }
    if (blk < 1024) {                       // pack x -> bf16
        const int i = (blk * 256 + t) * 8;
        float4 a = *(const float4*)&x[i];
        float4 b = *(const float4*)&x[i + 4];
        union { ushort us[8]; uint4 v; } pk;
        pk.us[0] = f2bf(a.x); pk.us[1] = f2bf(a.y); pk.us[2] = f2bf(a.z); pk.us[3] = f2bf(a.w);
        pk.us[4] = f2bf(b.x); pk.us[5] = f2bf(b.y); pk.us[6] = f2bf(b.z); pk.us[7] = f2bf(b.w);
        *(uint4*)&xb[i] = pk.v;
        return;
    }
    const float* w; ushort* wT; int K, N, n0, k0;
    if (blk < 1216) { const int s = blk - 1024; w = w_qkv; wT = wqkvT; K = 512; N = 1536; n0 = (s % 24) * 64; k0 = (s / 24) * 64; }
    else            { const int s = blk - 1216; w = w_out; wT = woutT; K = 512; N = 512;  n0 = (s % 8) * 64;  k0 = (s / 8) * 64; }
#pragma unroll
    for (int i = 0; i < 4; ++i) {
        const int slot = t + i * 256;
        const int r = slot >> 4, c4 = (slot & 15) * 4;
        float4 v = *(const float4*)&w[(size_t)(k0 + r) * N + n0 + c4];
        tile[c4 + 0][r] = f2bf(v.x);
        tile[c4 + 1][r] = f2bf(v.y);
        tile[c4 + 2][r] = f2bf(v.z);
        tile[c4 + 3][r] = f2bf(v.w);
    }
    __syncthreads();
    const int n = t >> 2, kc = (t & 3) * 16;
    union { ushort us[16]; uint4 v[2]; } o;
#pragma unroll
    for (int j = 0; j < 16; ++j) o.us[j] = tile[n][kc + j];
    *(uint4*)&wT[(size_t)(n0 + n) * K + k0 + kc]     = o.v[0];
    *(uint4*)&wT[(size_t)(n0 + n) * K + k0 + kc + 8] = o.v[1];
}

// ---------- QKV GEMM 64x128, global_load_lds staging, + RoPE epilogue ----
__global__ __launch_bounds__(256)
void gemm_qkv_rope(const ushort* __restrict__ xb, const ushort* __restrict__ wT,
                   ushort* __restrict__ qb, ushort* __restrict__ kb,
                   ushort* __restrict__ vtb, const float2* __restrict__ rope_tbl)
{
    __shared__ __align__(16) ushort As[64][64];    // unpadded: DMA target
    __shared__ __align__(16) ushort Bs[128][64];
    const int t = threadIdx.x, lane = t & 63, w = t >> 6;
    const int quad = lane >> 4, l16 = lane & 15;
    const int m0 = blockIdx.y * 64, n0 = blockIdx.x * 128;
    const int mw = (w >> 1) * 32, nw = (w & 1) * 64;
    const int krow = lane >> 3, kcol = (lane & 7) * 8;   // DMA lane mapping
    f32x4 acc[2][4] = {};

    for (int k0 = 0; k0 < 512; k0 += 64) {
        __syncthreads();   // previous tile's readers done
        gld16(&xb[(size_t)(m0 + w * 8 + krow) * 512 + k0 + kcol],        &As[w * 8][0]);
        gld16(&xb[(size_t)(m0 + (w + 4) * 8 + krow) * 512 + k0 + kcol],  &As[(w + 4) * 8][0]);
#pragma unroll
        for (int jj = 0; jj < 4; ++jj) {
            const int j = w * 4 + jj;
            gld16(&wT[(size_t)(n0 + j * 8 + krow) * 512 + k0 + kcol], &Bs[j * 8][0]);
        }
        __syncthreads();   // vmcnt drained -> tiles ready
#pragma unroll
        for (int ks = 0; ks < 2; ++ks) {
            short8 a[2], b[4];
#pragma unroll
            for (int i = 0; i < 2; ++i)
                a[i] = *(const short8*)&As[mw + i * 16 + l16][ks * 32 + quad * 8];
#pragma unroll
            for (int j = 0; j < 4; ++j)
                b[j] = *(const short8*)&Bs[nw + j * 16 + l16][ks * 32 + quad * 8];
#pragma unroll
            for (int i = 0; i < 2; ++i)
#pragma unroll
                for (int j = 0; j < 4; ++j)
                    acc[i][j] = mfma16(a[i], b[j], acc[i][j]);
        }
    }

    const int sec = (n0 + nw) >> 9;   // 0=q 1=k 2=v, wave-uniform
    if (sec == 2) {
#pragma unroll
        for (int i = 0; i < 2; ++i) {
            const int m = m0 + mw + i * 16 + quad * 4;
            const int bidx = m >> 11, n = m & 2047;
#pragma unroll
            for (int j = 0; j < 4; ++j) {
                const int nc = n0 + nw + j * 16 + l16;
                const int d = nc & 63, h = (nc >> 6) & 7;
                ushort4 pk;
                pk.x = f2bf(acc[i][j][0]); pk.y = f2bf(acc[i][j][1]);
                pk.z = f2bf(acc[i][j][2]); pk.w = f2bf(acc[i][j][3]);
                *(ushort4*)&vtb[(((size_t)bidx * 8 + h) * 64 + d) * 2048 + n] = pk;
            }
        }
    } else {
        ushort* dst = (sec == 0) ? qb : kb;
        const float scale = (sec == 0) ? 0.125f : 1.0f;
#pragma unroll
        for (int j = 0; j < 4; ++j) {
            const int nc = n0 + nw + j * 16 + l16;
            const int d = nc & 63, h = (nc >> 6) & 7;
            const float2* tb = rope_tbl + (d >> 1);
#pragma unroll
            for (int i = 0; i < 2; ++i)
#pragma unroll
            for (int r = 0; r < 4; ++r) {
                const int m = m0 + mw + i * 16 + quad * 4 + r;
                const int bidx = m >> 11, n = m & 2047;
                const float2 cs2 = tb[(size_t)n * 32];
                const float vacc = acc[i][j][r];
                const float partner = __shfl_xor(vacc, 1);
                const float rot = (d & 1) ? (vacc * cs2.x + partner * cs2.y)
                                          : (vacc * cs2.x - partner * cs2.y);
                dst[(((size_t)bidx * 8 + h) * 2048 + n) * 64 + d] = f2bf(rot * scale);
            }
        }
    }
}

// ---- flash R5: both-batch bias sharing + kv-split x4 partials -----------
// pos_bias is batch-independent => one block handles BOTH b for its
// (q-tile, h), alternating b per kv-tile and reusing ONE bias reg-set for
// the b0/b1 pair: bias requested bytes halve to the 128 MB compulsory.
// kv-split x4 restores 512 blocks = 2 blocks/CU (R4's 256 = 1/CU exposed
// every barrier stall). Partial fp32 O + row-sums; combine_o normalizes.
// Schedule per iter = R3/R4's proven one: counted vmcnt, ONE barrier/iter,
// triple-buffered K/V LDS, setprio around MFMA.
// VMEM ledger (per wave): prologue = Q[4](pinned first), s0[2], s1[2],
// bias0[16]. Iter i body: W, barrier, stage(i+2)[2] (if i+2<16), CORE,
// bias((i>>1)+1)[16] at odd i (if tile<8). Newer-than-stage(i) at W_i = 18
// for all i<15 (one bias + one stage between issue and wait); W_15 = 16.
__global__ __launch_bounds__(512, 4)
void flash_attn_mfma(const ushort* __restrict__ qb, const ushort* __restrict__ kb,
                     const ushort* __restrict__ vtb, const float* __restrict__ bias,
                     float* __restrict__ opart, float* __restrict__ lpart)
{
    __shared__ __align__(16) ushort Ks[3][64][64];   // 24KB, swizzled, DMA tgt
    __shared__ __align__(16) ushort Vt[3][64][64];   // 24KB, [dim][seq], swz
    __shared__ __align__(16) ushort Ps[8][16][72];   // 18KB
    const int t = threadIdx.x, lane = t & 63, w = t >> 6;   // w in [0,8)
    const int quad = lane >> 4, l16 = lane & 15;
    const int q0 = blockIdx.x * 128, h = blockIdx.y, ksp = blockIdx.z;
    const int kv0 = ksp * 512;                       // this split's kv range
    const ushort* Q0  = qb  + (size_t)h * SEQ * HDIM;
    const ushort* Q1  = qb  + (size_t)(8 + h) * SEQ * HDIM;
    const ushort* Kp0 = kb  + (size_t)h * SEQ * HDIM;
    const ushort* Kp1 = kb  + (size_t)(8 + h) * SEQ * HDIM;
    const ushort* VT0 = vtb + (size_t)h * HDIM * SEQ;
    const ushort* VT1 = vtb + (size_t)(8 + h) * HDIM * SEQ;
    const float*  Bp  = bias + ((size_t)h * SEQ + q0 + w * 16) * SEQ + kv0;

    f32x4 oacc0[4] = {}, oacc1[4] = {};
    float lsum0[4] = {}, lsum1[4] = {};
    const int krow = lane >> 3;                       // K/V DMA row-in-8
    const int kcolsw = ((lane & 7) ^ krow) * 8;       // swizzled source chunk
    const int sw = l16 & 7;
    const int c0 = (quad ^ sw) * 8;                   // swizzled read col ks=0
    const int c1 = ((quad + 4) ^ sw) * 8;             // ks=1

    // Q for both batches, pinned BEFORE any staging (vmcnt ledger!)
    short8 qf0[2], qf1[2];
    qf0[0] = *(const short8*)&Q0[(size_t)(q0 + w * 16 + l16) * HDIM + quad * 8];
    qf0[1] = *(const short8*)&Q0[(size_t)(q0 + w * 16 + l16) * HDIM + 32 + quad * 8];
    qf1[0] = *(const short8*)&Q1[(size_t)(q0 + w * 16 + l16) * HDIM + quad * 8];
    qf1[1] = *(const short8*)&Q1[(size_t)(q0 + w * 16 + l16) * HDIM + 32 + quad * 8];
    asm volatile("" ::: "memory");

    float breg[16];   // ONE bias reg-set, shared by the b0/b1 iter pair

#define FA_STAGE(BUF, TILE, KPp, VTp)                                               \
    {                                                                               \
        const int k2_ = kv0 + (TILE) * 64;                                          \
        gld16(&KPp[(size_t)(k2_ + w * 8 + krow) * HDIM + kcolsw], &Ks[BUF][w * 8][0]); \
        gld16(&VTp[(size_t)(w * 8 + krow) * SEQ + k2_ + kcolsw],  &Vt[BUF][w * 8][0]); \
    }

#define FA_BIAS(TILE)                                                               \
    {                                                                               \
        const int k2_ = (TILE) * 64;                                                \
        _Pragma("unroll")                                                           \
        for (int r = 0; r < 4; ++r)                                                 \
            _Pragma("unroll")                                                       \
            for (int s = 0; s < 4; ++s)                                             \
                breg[r * 4 + s] = Bp[(size_t)(quad * 4 + r) * SEQ + k2_ + s * 16 + l16]; \
    }

#define FA_CORE(IT, QF, OACC, LSUM)                                                 \
    {                                                                               \
        const int cb_ = (IT) % 3;                                                   \
        f32x4 sacc[4] = {};                                                         \
        __builtin_amdgcn_s_setprio(1);                                              \
        _Pragma("unroll")                                                           \
        for (int s = 0; s < 4; ++s) {                                               \
            short8 kf0 = *(const short8*)&Ks[cb_][s * 16 + l16][c0];                \
            sacc[s] = mfma16(QF[0], kf0, sacc[s]);                                  \
            short8 kf1 = *(const short8*)&Ks[cb_][s * 16 + l16][c1];                \
            sacc[s] = mfma16(QF[1], kf1, sacc[s]);                                  \
        }                                                                           \
        __builtin_amdgcn_s_setprio(0);                                              \
        _Pragma("unroll")                                                           \
        for (int r = 0; r < 4; ++r)                                                 \
            _Pragma("unroll")                                                       \
            for (int s = 0; s < 4; ++s) {                                           \
                const float p = __expf(sacc[s][r] + breg[r * 4 + s]);               \
                LSUM[r] += p;                                                       \
                Ps[w][quad * 4 + r][s * 16 + l16] = f2bf(p);                        \
            }                                                                       \
        asm volatile("" ::: "memory");   /* Ps writes before Ps reads */            \
        __builtin_amdgcn_s_setprio(1);                                              \
        _Pragma("unroll")                                                           \
        for (int ks2 = 0; ks2 < 2; ++ks2) {                                         \
            short8 pf = *(const short8*)&Ps[w][l16][ks2 * 32 + quad * 8];           \
            const int cc_ = ks2 ? c1 : c0;                                          \
            _Pragma("unroll")                                                       \
            for (int s = 0; s < 4; ++s) {                                           \
                short8 vf = *(const short8*)&Vt[cb_][s * 16 + l16][cc_];            \
                oacc_dummy                                                          \
            }                                                                       \
        }                                                                           \
        __builtin_amdgcn_s_setprio(0);                                              \
    }
#undef FA_CORE
#define FA_CORE(IT, QF, OACC, LSUM)                                                 \
    {                                                                               \
        const int cb_ = (IT) % 3;                                                   \
        f32x4 sacc[4] = {};                                                         \
        __builtin_amdgcn_s_setprio(1);                                              \
        _Pragma("unroll")                                                           \
        for (int s = 0; s < 4; ++s) {                                               \
            short8 kf0 = *(const short8*)&Ks[cb_][s * 16 + l16][c0];                \
            sacc[s] = mfma16(QF[0], kf0, sacc[s]);                                  \
            short8 kf1 = *(const short8*)&Ks[cb_][s * 16 + l16][c1];                \
            sacc[s] = mfma16(QF[1], kf1, sacc[s]);                                  \
        }                                                                           \
        __builtin_amdgcn_s_setprio(0);                                              \
        _Pragma("unroll")                                                           \
        for (int r = 0; r < 4; ++r)                                                 \
            _Pragma("unroll")                                                       \
            for (int s = 0; s < 4; ++s) {                                           \
                const float p = __expf(sacc[s][r] + breg[r * 4 + s]);               \
                LSUM[r] += p;                                                       \
                Ps[w][quad * 4 + r][s * 16 + l16] = f2bf(p);                        \
            }                                                                       \
        asm volatile("" ::: "memory");   /* Ps writes before Ps reads */            \
        __builtin_amdgcn_s_setprio(1);                                              \
        _Pragma("unroll")                                                           \
        for (int ks2 = 0; ks2 < 2; ++ks2) {                                         \
            short8 pf = *(const short8*)&Ps[w][l16][ks2 * 32 + quad * 8];           \
            const int cc_ = ks2 ? c1 : c0;                                          \
            _Pragma("unroll")                                                       \
            for (int s = 0; s < 4; ++s) {                                           \
                short8 vf = *(const short8*)&Vt[cb_][s * 16 + l16][cc_];            \
                OACC[s] = mfma16(pf, vf, OACC[s]);                                  \
            }                                                                       \
        }                                                                           \
        __builtin_amdgcn_s_setprio(0);                                              \
    }

#define FA_W(N) asm volatile("s_waitcnt vmcnt(" #N ")" ::: "memory")

    // prologue: stage iter0 (tile0,b0) + iter1 (tile0,b1), then bias tile 0
    FA_STAGE(0, 0, Kp0, VT0);
    FA_STAGE(1, 0, Kp1, VT1);
    FA_BIAS(0);

#pragma unroll
    for (int T = 0; T < 7; ++T) {
        // iter 2T (b0)
        FA_W(18);
        __builtin_amdgcn_s_barrier();
        FA_STAGE((2 * T + 2) % 3, T + 1, Kp0, VT0);
        FA_CORE(2 * T, qf0, oacc0, lsum0);
        // iter 2T+1 (b1)
        FA_W(18);
        __builtin_amdgcn_s_barrier();
        FA_STAGE((2 * T + 3) % 3, T + 1, Kp1, VT1);
        FA_CORE(2 * T + 1, qf1, oacc1, lsum1);
        FA_BIAS(T + 1);   // refill AFTER last use of tile T (this iter's softmax)
    }
    // tail pair T=7: no stage, no refill
    FA_W(18);
    __builtin_amdgcn_s_barrier();
    FA_CORE(14, qf0, oacc0, lsum0);
    FA_W(16);
    __builtin_amdgcn_s_barrier();
    FA_CORE(15, qf1, oacc1, lsum1);

#undef FA_W
#undef FA_CORE
#undef FA_BIAS
#undef FA_STAGE

    // epilogue: partial row-sums + fp32 partial O for this kv-split
    const size_t obase = (size_t)ksp * (4096 * 512);
#define FA_EPI(OACC, LSUM, BB)                                                      \
    {                                                                               \
        _Pragma("unroll")                                                           \
        for (int r = 0; r < 4; ++r) {                                               \
            float rs = LSUM[r];                                                     \
            rs += __shfl_xor(rs, 1, 16);                                            \
            rs += __shfl_xor(rs, 2, 16);                                            \
            rs += __shfl_xor(rs, 4, 16);                                            \
            rs += __shfl_xor(rs, 8, 16);                                            \
            const int q = q0 + w * 16 + quad * 4 + r;                               \
            const size_t m = (size_t)(BB) * SEQ + q;                                \
            if (l16 == 0)                                                           \
                lpart[(((size_t)ksp * NHEAD + h) * 2 + (BB)) * SEQ + q] = rs;       \
            _Pragma("unroll")                                                       \
            for (int s = 0; s < 4; ++s)                                             \
                opart[obase + m * 512 + h * 64 + s * 16 + l16] = OACC[s][r];        \
        }                                                                           \
    }
    FA_EPI(oacc0, lsum0, 0);
    FA_EPI(oacc1, lsum1, 1);
#undef FA_EPI
}

// ---- combine kv-split partials -> normalized bf16 attnb [4096][512] -----
__global__ __launch_bounds__(256)
void combine_o(const float* __restrict__ opart, const float* __restrict__ lpart,
               ushort* __restrict__ ob)
{
    const int idx = blockIdx.x * 256 + threadIdx.x;   // 0..524287
    const int m = idx >> 7;                           // row 0..4095
    const int c4 = (idx & 127) * 4;                   // col 0,4,..508
    const int h = c4 >> 6, bb = m >> 11, q = m & 2047;
    float4 acc = make_float4(0.f, 0.f, 0.f, 0.f);
    float l = 0.f;
#pragma unroll
    for (int s = 0; s < 4; ++s) {
        const float4 p = *(const float4*)&opart[(size_t)s * (4096 * 512) + (size_t)m * 512 + c4];
        acc.x += p.x; acc.y += p.y; acc.z += p.z; acc.w += p.w;
        l += lpart[(((size_t)s * NHEAD + h) * 2 + bb) * SEQ + q];
    }
    const float inv = 1.0f / l;
    ushort4 o;
    o.x = f2bf(acc.x * inv); o.y = f2bf(acc.y * inv);
    o.z = f2bf(acc.z * inv); o.w = f2bf(acc.w * inv);
    *(ushort4*)&ob[(size_t)m * 512 + c4] = o;
}

// ---------- out GEMM 64x64, global_load_lds staging ----------------------
__global__ __launch_bounds__(256)
void gemm_out(const ushort* __restrict__ Ab, const ushort* __restrict__ wT,
              float* __restrict__ C)
{
    __shared__ __align__(16) ushort As[64][64];
    __shared__ __align__(16) ushort Bs[64][64];
    const int t = threadIdx.x, lane = t & 63, w = t >> 6;
    const int quad = lane >> 4, l16 = lane & 15;
    const int m0 = blockIdx.y * 64, n0 = blockIdx.x * 64;
    const int mw = (w >> 1) * 32, nw = (w & 1) * 32;
    const int krow = lane >> 3, kcol = (lane & 7) * 8;
    f32x4 acc[2][2] = {};

    for (int k0 = 0; k0 < 512; k0 += 64) {
        __syncthreads();
        gld16(&Ab[(size_t)(m0 + w * 8 + krow) * 512 + k0 + kcol],       &As[w * 8][0]);
        gld16(&Ab[(size_t)(m0 + (w + 4) * 8 + krow) * 512 + k0 + kcol], &As[(w + 4) * 8][0]);
        gld16(&wT[(size_t)(n0 + w * 8 + krow) * 512 + k0 + kcol],       &Bs[w * 8][0]);
        gld16(&wT[(size_t)(n0 + (w + 4) * 8 + krow) * 512 + k0 + kcol], &Bs[(w + 4) * 8][0]);
        __syncthreads();
#pragma unroll
        for (int ks = 0; ks < 2; ++ks) {
            short8 a[2], b[2];
#pragma unroll
            for (int i = 0; i < 2; ++i)
                a[i] = *(const short8*)&As[mw + i * 16 + l16][ks * 32 + quad * 8];
#pragma unroll
            for (int j = 0; j < 2; ++j)
                b[j] = *(const short8*)&Bs[nw + j * 16 + l16][ks * 32 + quad * 8];
#pragma unroll
            for (int i = 0; i < 2; ++i)
#pragma unroll
                for (int j = 0; j < 2; ++j)
                    acc[i][j] = mfma16(a[i], b[j], acc[i][j]);
        }
    }
#pragma unroll
    for (int i = 0; i < 2; ++i)
#pragma unroll
    for (int r = 0; r < 4; ++r) {
        const int m = m0 + mw + i * 16 + quad * 4 + r;
#pragma unroll
        for (int j = 0; j < 2; ++j)
            C[(size_t)m * 512 + n0 + nw + j * 16 + l16] = acc[i][j][r];
    }
}

extern "C" void kernel_launch(void* const* d_in, const int* in_sizes, int n_in,
                              void* d_out, int out_size, void* d_ws, size_t ws_size,
                              hipStream_t stream)
{
    const float* x        = (const float*)d_in[0];
    const float* pos_bias = (const float*)d_in[1];
    const float* w_qkv    = (const float*)d_in[2];
    const float* w_out    = (const float*)d_in[3];
    float* out = (float*)d_out;

    char* ws = (char*)d_ws;
    ushort* xb     = (ushort*)(ws);                            // 4 MB
    ushort* wqkvT  = (ushort*)(ws + 4194304);                  // 1.5 MB
    ushort* woutT  = (ushort*)(ws + 5767168);                  // 0.5 MB
    ushort* qb     = (ushort*)(ws + 6291456);                  // 4 MB
    ushort* kb     = (ushort*)(ws + 10485760);                 // 4 MB
    ushort* vtb    = (ushort*)(ws + 14680064);                 // 4 MB (V^T)
    ushort* attnb  = (ushort*)(ws + 18874368);                 // 4 MB
    float2* ropetb = (float2*)(ws + 23068672);                 // 512 KB
    float*  opart  = (float*)(ws + 25165824);                  // 32 MB (4 splits)
    float*  lpart  = (float*)(ws + 58720256);                  // 512 KB

    prep<<<1296, 256, 0, stream>>>(x, w_qkv, w_out, xb, wqkvT, woutT, ropetb);
    gemm_qkv_rope<<<dim3(12, 64), 256, 0, stream>>>(xb, wqkvT, qb, kb, vtb, ropetb);
    flash_attn_mfma<<<dim3(SEQ / 128, NHEAD, 4), 512, 0, stream>>>(qb, kb, vtb, pos_bias, opart, lpart);
    combine_o<<<2048, 256, 0, stream>>>(opart, lpart, attnb);
    gemm_out<<<dim3(8, 64), 256, 0, stream>>>(attnb, woutT, out);
}

// Round 6
// 263.504 us; speedup vs baseline: 1.3793x; 1.3793x over previous
//
#include <hip/hip_runtime.h>
#include <math.h>

#define SEQ 2048
#define NHEAD 8
#define HDIM 64
#define BATCH 2

typedef __attribute__((ext_vector_type(8))) short short8;
typedef __attribute__((ext_vector_type(4))) float f32x4;

__device__ __forceinline__ ushort f2bf(float f) {
    union { float f; unsigned u; } v; v.f = f;
    unsigned r = v.u + 0x7FFFu + ((v.u >> 16) & 1u);   // RNE
    return (ushort)(r >> 16);
}

__device__ __forceinline__ f32x4 mfma16(short8 a, short8 b, f32x4 c) {
    return __builtin_amdgcn_mfma_f32_16x16x32_bf16(a, b, c, 0, 0, 0);
}

// global->LDS DMA, 16B per lane; ldsp must be wave-uniform (lane i lands at
// ldsp + i*16).
__device__ __forceinline__ void gld16(const void* g, void* l) {
    __builtin_amdgcn_global_load_lds(
        (const __attribute__((address_space(1))) unsigned int*)g,
        (__attribute__((address_space(3))) unsigned int*)l, 16, 0, 0);
}

// ------- fused prep: pack x + transpose both weights + RoPE table --------
__global__ __launch_bounds__(256)
void prep(const float* __restrict__ x, const float* __restrict__ w_qkv,
          const float* __restrict__ w_out, ushort* __restrict__ xb,
          ushort* __restrict__ wqkvT, ushort* __restrict__ woutT,
          float2* __restrict__ rope_tbl)
{
    __shared__ ushort tile[64][66];
    const int blk = blockIdx.x, t = threadIdx.x;
    if (blk >= 1280) {                      // RoPE cos/sin table [2048][32]
        const int idx = (blk - 1280) * 256 + t;      // 0..4095
        const int n = idx >> 1, fbase = (idx & 1) * 16;
#pragma unroll
        for (int f = 0; f < 16; ++f) {
            const float inv = __expf(-(float)(fbase + f) * (9.2103403719761836f / 32.0f));
            float sn, cs;
            __sincosf((float)n * inv, &sn, &cs);
            rope_tbl[(size_t)n * 32 + fbase + f] = make_float2(cs, sn);
        }
        return;
    }
    if (blk < 1024) {                       // pack x -> bf16
        const int i = (blk * 256 + t) * 8;
        float4 a = *(const float4*)&x[i];
        float4 b = *(const float4*)&x[i + 4];
        union { ushort us[8]; uint4 v; } pk;
        pk.us[0] = f2bf(a.x); pk.us[1] = f2bf(a.y); pk.us[2] = f2bf(a.z); pk.us[3] = f2bf(a.w);
        pk.us[4] = f2bf(b.x); pk.us[5] = f2bf(b.y); pk.us[6] = f2bf(b.z); pk.us[7] = f2bf(b.w);
        *(uint4*)&xb[i] = pk.v;
        return;
    }
    const float* w; ushort* wT; int K, N, n0, k0;
    if (blk < 1216) { const int s = blk - 1024; w = w_qkv; wT = wqkvT; K = 512; N = 1536; n0 = (s % 24) * 64; k0 = (s / 24) * 64; }
    else            { const int s = blk - 1216; w = w_out; wT = woutT; K = 512; N = 512;  n0 = (s % 8) * 64;  k0 = (s / 8) * 64; }
#pragma unroll
    for (int i = 0; i < 4; ++i) {
        const int slot = t + i * 256;
        const int r = slot >> 4, c4 = (slot & 15) * 4;
        float4 v = *(const float4*)&w[(size_t)(k0 + r) * N + n0 + c4];
        tile[c4 + 0][r] = f2bf(v.x);
        tile[c4 + 1][r] = f2bf(v.y);
        tile[c4 + 2][r] = f2bf(v.z);
        tile[c4 + 3][r] = f2bf(v.w);
    }
    __syncthreads();
    const int n = t >> 2, kc = (t & 3) * 16;
    union { ushort us[16]; uint4 v[2]; } o;
#pragma unroll
    for (int j = 0; j < 16; ++j) o.us[j] = tile[n][kc + j];
    *(uint4*)&wT[(size_t)(n0 + n) * K + k0 + kc]     = o.v[0];
    *(uint4*)&wT[(size_t)(n0 + n) * K + k0 + kc + 8] = o.v[1];
}

// ---------- QKV GEMM 64x128, global_load_lds staging, + RoPE epilogue ----
__global__ __launch_bounds__(256)
void gemm_qkv_rope(const ushort* __restrict__ xb, const ushort* __restrict__ wT,
                   ushort* __restrict__ qb, ushort* __restrict__ kb,
                   ushort* __restrict__ vtb, const float2* __restrict__ rope_tbl)
{
    __shared__ __align__(16) ushort As[64][64];    // unpadded: DMA target
    __shared__ __align__(16) ushort Bs[128][64];
    const int t = threadIdx.x, lane = t & 63, w = t >> 6;
    const int quad = lane >> 4, l16 = lane & 15;
    const int m0 = blockIdx.y * 64, n0 = blockIdx.x * 128;
    const int mw = (w >> 1) * 32, nw = (w & 1) * 64;
    const int krow = lane >> 3, kcol = (lane & 7) * 8;   // DMA lane mapping
    f32x4 acc[2][4] = {};

    for (int k0 = 0; k0 < 512; k0 += 64) {
        __syncthreads();   // previous tile's readers done
        gld16(&xb[(size_t)(m0 + w * 8 + krow) * 512 + k0 + kcol],        &As[w * 8][0]);
        gld16(&xb[(size_t)(m0 + (w + 4) * 8 + krow) * 512 + k0 + kcol],  &As[(w + 4) * 8][0]);
#pragma unroll
        for (int jj = 0; jj < 4; ++jj) {
            const int j = w * 4 + jj;
            gld16(&wT[(size_t)(n0 + j * 8 + krow) * 512 + k0 + kcol], &Bs[j * 8][0]);
        }
        __syncthreads();   // vmcnt drained -> tiles ready
#pragma unroll
        for (int ks = 0; ks < 2; ++ks) {
            short8 a[2], b[4];
#pragma unroll
            for (int i = 0; i < 2; ++i)
                a[i] = *(const short8*)&As[mw + i * 16 + l16][ks * 32 + quad * 8];
#pragma unroll
            for (int j = 0; j < 4; ++j)
                b[j] = *(const short8*)&Bs[nw + j * 16 + l16][ks * 32 + quad * 8];
#pragma unroll
            for (int i = 0; i < 2; ++i)
#pragma unroll
                for (int j = 0; j < 4; ++j)
                    acc[i][j] = mfma16(a[i], b[j], acc[i][j]);
        }
    }

    const int sec = (n0 + nw) >> 9;   // 0=q 1=k 2=v, wave-uniform
    if (sec == 2) {
#pragma unroll
        for (int i = 0; i < 2; ++i) {
            const int m = m0 + mw + i * 16 + quad * 4;
            const int bidx = m >> 11, n = m & 2047;
#pragma unroll
            for (int j = 0; j < 4; ++j) {
                const int nc = n0 + nw + j * 16 + l16;
                const int d = nc & 63, h = (nc >> 6) & 7;
                ushort4 pk;
                pk.x = f2bf(acc[i][j][0]); pk.y = f2bf(acc[i][j][1]);
                pk.z = f2bf(acc[i][j][2]); pk.w = f2bf(acc[i][j][3]);
                *(ushort4*)&vtb[(((size_t)bidx * 8 + h) * 64 + d) * 2048 + n] = pk;
            }
        }
    } else {
        ushort* dst = (sec == 0) ? qb : kb;
        const float scale = (sec == 0) ? 0.125f : 1.0f;
#pragma unroll
        for (int j = 0; j < 4; ++j) {
            const int nc = n0 + nw + j * 16 + l16;
            const int d = nc & 63, h = (nc >> 6) & 7;
            const float2* tb = rope_tbl + (d >> 1);
#pragma unroll
            for (int i = 0; i < 2; ++i)
#pragma unroll
            for (int r = 0; r < 4; ++r) {
                const int m = m0 + mw + i * 16 + quad * 4 + r;
                const int bidx = m >> 11, n = m & 2047;
                const float2 cs2 = tb[(size_t)n * 32];
                const float vacc = acc[i][j][r];
                const float partner = __shfl_xor(vacc, 1);
                const float rot = (d & 1) ? (vacc * cs2.x + partner * cs2.y)
                                          : (vacc * cs2.x - partner * cs2.y);
                dst[(((size_t)bidx * 8 + h) * 2048 + n) * 64 + d] = f2bf(rot * scale);
            }
        }
    }
}

// ---- flash R6: R3 schedule + batch-alternating iters + kv-split x2 ------
// R5 failed via launch_bounds(512,4)-forced spills (VGPR 64, scratch =
// 206MB WRITE) + broken vmcnt ledger. R6 returns to R3's PROVEN schedule
// verbatim (QBLK=64, 256thr, tri-buffered K/V, stage[4]+bias[16] uniform
// per iter, W(36)/W(16)) and gets the bias halving safely:
//  - iters alternate batch (even=b0, odd=b1); (it+2) has same parity, so
//    each iter stages/refills for its OWN batch -> ledger unchanged.
//  - two bias slots as in R3; the b0/b1 slots of a tile load the SAME
//    addresses (2nd read is L1/L2-hot, costs no LLC/HBM delivery).
//  - kv-split x2 keeps grid at 512 blocks = 2 blocks/CU (LDS 58KB).
//  - fp32 partial O + partial row-sums; combine_o normalizes.
// NO launch_bounds min-waves arg (R5 lesson).
__global__ __launch_bounds__(256)
void flash_attn_mfma(const ushort* __restrict__ qb, const ushort* __restrict__ kb,
                     const ushort* __restrict__ vtb, const float* __restrict__ bias,
                     float* __restrict__ opart, float* __restrict__ lpart)
{
    __shared__ __align__(16) ushort Ks[3][64][64];   // 24KB, swizzled, DMA tgt
    __shared__ __align__(16) ushort Vt[3][64][64];   // 24KB, [dim][seq], swz
    __shared__ __align__(16) ushort Ps[4][16][72];   // 9KB
    const int t = threadIdx.x, lane = t & 63, w = t >> 6;   // w in [0,4)
    const int quad = lane >> 4, l16 = lane & 15;
    const int q0 = blockIdx.x * 64, h = blockIdx.y, ksp = blockIdx.z;
    const int kv0 = ksp * 1024;                      // this split's kv range
    const ushort* Q0  = qb  + (size_t)h * SEQ * HDIM;
    const ushort* Q1  = qb  + (size_t)(NHEAD + h) * SEQ * HDIM;
    const ushort* Kp0 = kb  + (size_t)h * SEQ * HDIM;
    const ushort* Kp1 = kb  + (size_t)(NHEAD + h) * SEQ * HDIM;
    const ushort* VT0 = vtb + (size_t)h * HDIM * SEQ;
    const ushort* VT1 = vtb + (size_t)(NHEAD + h) * HDIM * SEQ;
    const float*  Bp  = bias + ((size_t)h * SEQ + q0 + w * 16) * SEQ + kv0;

    f32x4 oacc0[4] = {}, oacc1[4] = {};
    float lsum0[4] = {}, lsum1[4] = {};
    const int krow = lane >> 3;                       // K/V DMA row-in-8
    const int kcolsw = ((lane & 7) ^ krow) * 8;       // swizzled source chunk
    const int sw = l16 & 7;
    const int c0 = (quad ^ sw) * 8;                   // swizzled read col ks=0
    const int c1 = ((quad + 4) ^ sw) * 8;             // ks=1

    // Q for both batches, pinned BEFORE any staging (vmcnt ledger: 4 loads)
    short8 qf0[2], qf1[2];
    qf0[0] = *(const short8*)&Q0[(size_t)(q0 + w * 16 + l16) * HDIM + quad * 8];
    qf0[1] = *(const short8*)&Q0[(size_t)(q0 + w * 16 + l16) * HDIM + 32 + quad * 8];
    qf1[0] = *(const short8*)&Q1[(size_t)(q0 + w * 16 + l16) * HDIM + quad * 8];
    qf1[1] = *(const short8*)&Q1[(size_t)(q0 + w * 16 + l16) * HDIM + 32 + quad * 8];
    asm volatile("" ::: "memory");

    float b0[16], b1[16];   // two bias slots (R3 pattern), parity = it&1

    // stage K/V tile TILE (batch via KPp/VTp) into LDS buffer BUF: 4 gld16
#define FA_STAGE(BUF, TILE, KPp, VTp)                                               \
    {                                                                               \
        const int k2_ = kv0 + (TILE) * 64;                                          \
        gld16(&KPp[(size_t)(k2_ + w * 8 + krow) * HDIM + kcolsw],       &Ks[BUF][w * 8][0]);       \
        gld16(&KPp[(size_t)(k2_ + (w + 4) * 8 + krow) * HDIM + kcolsw], &Ks[BUF][(w + 4) * 8][0]); \
        gld16(&VTp[(size_t)(w * 8 + krow) * SEQ + k2_ + kcolsw],        &Vt[BUF][w * 8][0]);       \
        gld16(&VTp[(size_t)((w + 4) * 8 + krow) * SEQ + k2_ + kcolsw],  &Vt[BUF][(w + 4) * 8][0]); \
    }

    // bias tile TILE -> 16 fp32 regs (row quad*4+r, col s*16+l16)
#define FA_BIAS(BREG, TILE)                                                         \
    {                                                                               \
        const int k2_ = (TILE) * 64;                                                \
        _Pragma("unroll")                                                           \
        for (int r = 0; r < 4; ++r)                                                 \
            _Pragma("unroll")                                                       \
            for (int s = 0; s < 4; ++s)                                             \
                BREG[r * 4 + s] = Bp[(size_t)(quad * 4 + r) * SEQ + k2_ + s * 16 + l16]; \
    }

    // one iteration (R3 body). IT: iter index (tile=IT>>1, batch=IT&1).
#define FA_BODY(IT, QF, OACC, LSUM, BREG, KPp, VTp, REFILL, WCNT)                   \
    {                                                                               \
        asm volatile("s_waitcnt vmcnt(" #WCNT ")" ::: "memory");                    \
        __builtin_amdgcn_s_barrier();                                               \
        const int cb_ = (IT) % 3;                                                   \
        if (REFILL) {                                                               \
            FA_STAGE(((IT) + 2) % 3, ((IT) + 2) >> 1, KPp, VTp);                    \
            asm volatile("" ::: "memory");   /* pin: stage before bias */           \
        }                                                                           \
        f32x4 sacc[4] = {};                                                         \
        __builtin_amdgcn_s_setprio(1);                                              \
        _Pragma("unroll")                                                           \
        for (int s = 0; s < 4; ++s) {                                               \
            short8 kf0 = *(const short8*)&Ks[cb_][s * 16 + l16][c0];                \
            sacc[s] = mfma16(QF[0], kf0, sacc[s]);                                  \
            short8 kf1 = *(const short8*)&Ks[cb_][s * 16 + l16][c1];                \
            sacc[s] = mfma16(QF[1], kf1, sacc[s]);                                  \
        }                                                                           \
        __builtin_amdgcn_s_setprio(0);                                              \
        _Pragma("unroll")                                                           \
        for (int r = 0; r < 4; ++r)                                                 \
            _Pragma("unroll")                                                       \
            for (int s = 0; s < 4; ++s) {                                           \
                const float p = __expf(sacc[s][r] + BREG[r * 4 + s]);               \
                LSUM[r] += p;                                                       \
                Ps[w][quad * 4 + r][s * 16 + l16] = f2bf(p);                        \
            }                                                                       \
        if (REFILL) FA_BIAS(BREG, ((IT) + 2) >> 1);                                 \
        asm volatile("" ::: "memory");   /* Ps writes before Ps reads */            \
        __builtin_amdgcn_s_setprio(1);                                              \
        _Pragma("unroll")                                                           \
        for (int ks2 = 0; ks2 < 2; ++ks2) {                                         \
            short8 pf = *(const short8*)&Ps[w][l16][ks2 * 32 + quad * 8];           \
            const int cc_ = ks2 ? c1 : c0;                                          \
            _Pragma("unroll")                                                       \
            for (int s = 0; s < 4; ++s) {                                           \
                short8 vf = *(const short8*)&Vt[cb_][s * 16 + l16][cc_];            \
                OACC[s] = mfma16(pf, vf, OACC[s]);                                  \
            }                                                                       \
        }                                                                           \
        __builtin_amdgcn_s_setprio(0);                                              \
    }

    // prologue: it0 (tile0,b0), it1 (tile0,b1); order pinned
    FA_STAGE(0, 0, Kp0, VT0);
    asm volatile("" ::: "memory");
    FA_BIAS(b0, 0);
    asm volatile("" ::: "memory");
    FA_STAGE(1, 0, Kp1, VT1);
    asm volatile("" ::: "memory");
    FA_BIAS(b1, 0);

    for (int T = 0; T < 15; ++T) {
        FA_BODY(2 * T,     qf0, oacc0, lsum0, b0, Kp0, VT0, 1, 36);
        FA_BODY(2 * T + 1, qf1, oacc1, lsum1, b1, Kp1, VT1, 1, 36);
    }
    FA_BODY(30, qf0, oacc0, lsum0, b0, Kp0, VT0, 0, 36);
    FA_BODY(31, qf1, oacc1, lsum1, b1, Kp1, VT1, 0, 16);

#undef FA_BODY
#undef FA_BIAS
#undef FA_STAGE

    // epilogue: partial row-sums + fp32 partial O for this kv-split
    const size_t obase = (size_t)ksp * (4096 * 512);
#define FA_EPI(OACC, LSUM, BB)                                                      \
    {                                                                               \
        _Pragma("unroll")                                                           \
        for (int r = 0; r < 4; ++r) {                                               \
            float rs = LSUM[r];                                                     \
            rs += __shfl_xor(rs, 1, 16);                                            \
            rs += __shfl_xor(rs, 2, 16);                                            \
            rs += __shfl_xor(rs, 4, 16);                                            \
            rs += __shfl_xor(rs, 8, 16);                                            \
            const int q = q0 + w * 16 + quad * 4 + r;                               \
            const size_t m = (size_t)(BB) * SEQ + q;                                \
            if (l16 == 0)                                                           \
                lpart[(((size_t)ksp * NHEAD + h) * 2 + (BB)) * SEQ + q] = rs;       \
            _Pragma("unroll")                                                       \
            for (int s = 0; s < 4; ++s)                                             \
                opart[obase + m * 512 + h * 64 + s * 16 + l16] = OACC[s][r];        \
        }                                                                           \
    }
    FA_EPI(oacc0, lsum0, 0);
    FA_EPI(oacc1, lsum1, 1);
#undef FA_EPI
}

// ---- combine kv-split partials -> normalized bf16 attnb [4096][512] -----
__global__ __launch_bounds__(256)
void combine_o(const float* __restrict__ opart, const float* __restrict__ lpart,
               ushort* __restrict__ ob)
{
    const int idx = blockIdx.x * 256 + threadIdx.x;   // 0..524287
    const int m = idx >> 7;                           // row 0..4095
    const int c4 = (idx & 127) * 4;                   // col 0,4,..508
    const int h = c4 >> 6, bb = m >> 11, q = m & 2047;
    float4 acc = make_float4(0.f, 0.f, 0.f, 0.f);
    float l = 0.f;
#pragma unroll
    for (int s = 0; s < 2; ++s) {
        const float4 p = *(const float4*)&opart[(size_t)s * (4096 * 512) + (size_t)m * 512 + c4];
        acc.x += p.x; acc.y += p.y; acc.z += p.z; acc.w += p.w;
        l += lpart[(((size_t)s * NHEAD + h) * 2 + bb) * SEQ + q];
    }
    const float inv = 1.0f / l;
    ushort4 o;
    o.x = f2bf(acc.x * inv); o.y = f2bf(acc.y * inv);
    o.z = f2bf(acc.z * inv); o.w = f2bf(acc.w * inv);
    *(ushort4*)&ob[(size_t)m * 512 + c4] = o;
}

// ---------- out GEMM 64x64, global_load_lds staging ----------------------
__global__ __launch_bounds__(256)
void gemm_out(const ushort* __restrict__ Ab, const ushort* __restrict__ wT,
              float* __restrict__ C)
{
    __shared__ __align__(16) ushort As[64][64];
    __shared__ __align__(16) ushort Bs[64][64];
    const int t = threadIdx.x, lane = t & 63, w = t >> 6;
    const int quad = lane >> 4, l16 = lane & 15;
    const int m0 = blockIdx.y * 64, n0 = blockIdx.x * 64;
    const int mw = (w >> 1) * 32, nw = (w & 1) * 32;
    const int krow = lane >> 3, kcol = (lane & 7) * 8;
    f32x4 acc[2][2] = {};

    for (int k0 = 0; k0 < 512; k0 += 64) {
        __syncthreads();
        gld16(&Ab[(size_t)(m0 + w * 8 + krow) * 512 + k0 + kcol],       &As[w * 8][0]);
        gld16(&Ab[(size_t)(m0 + (w + 4) * 8 + krow) * 512 + k0 + kcol], &As[(w + 4) * 8][0]);
        gld16(&wT[(size_t)(n0 + w * 8 + krow) * 512 + k0 + kcol],       &Bs[w * 8][0]);
        gld16(&wT[(size_t)(n0 + (w + 4) * 8 + krow) * 512 + k0 + kcol], &Bs[(w + 4) * 8][0]);
        __syncthreads();
#pragma unroll
        for (int ks = 0; ks < 2; ++ks) {
            short8 a[2], b[2];
#pragma unroll
            for (int i = 0; i < 2; ++i)
                a[i] = *(const short8*)&As[mw + i * 16 + l16][ks * 32 + quad * 8];
#pragma unroll
            for (int j = 0; j < 2; ++j)
                b[j] = *(const short8*)&Bs[nw + j * 16 + l16][ks * 32 + quad * 8];
#pragma unroll
            for (int i = 0; i < 2; ++i)
#pragma unroll
                for (int j = 0; j < 2; ++j)
                    acc[i][j] = mfma16(a[i], b[j], acc[i][j]);
        }
    }
#pragma unroll
    for (int i = 0; i < 2; ++i)
#pragma unroll
    for (int r = 0; r < 4; ++r) {
        const int m = m0 + mw + i * 16 + quad * 4 + r;
#pragma unroll
        for (int j = 0; j < 2; ++j)
            C[(size_t)m * 512 + n0 + nw + j * 16 + l16] = acc[i][j][r];
    }
}

extern "C" void kernel_launch(void* const* d_in, const int* in_sizes, int n_in,
                              void* d_out, int out_size, void* d_ws, size_t ws_size,
                              hipStream_t stream)
{
    const float* x        = (const float*)d_in[0];
    const float* pos_bias = (const float*)d_in[1];
    const float* w_qkv    = (const float*)d_in[2];
    const float* w_out    = (const float*)d_in[3];
    float* out = (float*)d_out;

    char* ws = (char*)d_ws;
    ushort* xb     = (ushort*)(ws);                            // 4 MB
    ushort* wqkvT  = (ushort*)(ws + 4194304);                  // 1.5 MB
    ushort* woutT  = (ushort*)(ws + 5767168);                  // 0.5 MB
    ushort* qb     = (ushort*)(ws + 6291456);                  // 4 MB
    ushort* kb     = (ushort*)(ws + 10485760);                 // 4 MB
    ushort* vtb    = (ushort*)(ws + 14680064);                 // 4 MB (V^T)
    ushort* attnb  = (ushort*)(ws + 18874368);                 // 4 MB
    float2* ropetb = (float2*)(ws + 23068672);                 // 512 KB
    float*  opart  = (float*)(ws + 25165824);                  // 16 MB (2 splits)
    float*  lpart  = (float*)(ws + 41943040);                  // 512 KB

    prep<<<1296, 256, 0, stream>>>(x, w_qkv, w_out, xb, wqkvT, woutT, ropetb);
    gemm_qkv_rope<<<dim3(12, 64), 256, 0, stream>>>(xb, wqkvT, qb, kb, vtb, ropetb);
    flash_attn_mfma<<<dim3(SEQ / 64, NHEAD, 2), 256, 0, stream>>>(qb, kb, vtb, pos_bias, opart, lpart);
    combine_o<<<2048, 256, 0, stream>>>(opart, lpart, attnb);
    gemm_out<<<dim3(8, 64), 256, 0, stream>>>(attnb, woutT, out);
}

// Round 7
// 260.339 us; speedup vs baseline: 1.3960x; 1.0122x over previous
//
#include <hip/hip_runtime.h>
#include <math.h>

#define SEQ 2048
#define NHEAD 8
#define HDIM 64
#define BATCH 2

typedef __attribute__((ext_vector_type(8))) short short8;
typedef __attribute__((ext_vector_type(4))) float f32x4;

__device__ __forceinline__ ushort f2bf(float f) {
    union { float f; unsigned u; } v; v.f = f;
    unsigned r = v.u + 0x7FFFu + ((v.u >> 16) & 1u);   // RNE
    return (ushort)(r >> 16);
}

__device__ __forceinline__ f32x4 mfma16(short8 a, short8 b, f32x4 c) {
    return __builtin_amdgcn_mfma_f32_16x16x32_bf16(a, b, c, 0, 0, 0);
}

// global->LDS DMA, 16B per lane; ldsp must be wave-uniform (lane i lands at
// ldsp + i*16).
__device__ __forceinline__ void gld16(const void* g, void* l) {
    __builtin_amdgcn_global_load_lds(
        (const __attribute__((address_space(1))) unsigned int*)g,
        (__attribute__((address_space(3))) unsigned int*)l, 16, 0, 0);
}

// ------- fused prep: pack x + transpose both weights + RoPE table --------
__global__ __launch_bounds__(256)
void prep(const float* __restrict__ x, const float* __restrict__ w_qkv,
          const float* __restrict__ w_out, ushort* __restrict__ xb,
          ushort* __restrict__ wqkvT, ushort* __restrict__ woutT,
          float2* __restrict__ rope_tbl)
{
    __shared__ ushort tile[64][66];
    const int blk = blockIdx.x, t = threadIdx.x;
    if (blk >= 1280) {                      // RoPE cos/sin table [2048][32]
        const int idx = (blk - 1280) * 256 + t;      // 0..4095
        const int n = idx >> 1, fbase = (idx & 1) * 16;
#pragma unroll
        for (int f = 0; f < 16; ++f) {
            const float inv = __expf(-(float)(fbase + f) * (9.2103403719761836f / 32.0f));
            float sn, cs;
            __sincosf((float)n * inv, &sn, &cs);
            rope_tbl[(size_t)n * 32 + fbase + f] = make_float2(cs, sn);
        }
        return;
    }
    if (blk < 1024) {                       // pack x -> bf16
        const int i = (blk * 256 + t) * 8;
        float4 a = *(const float4*)&x[i];
        float4 b = *(const float4*)&x[i + 4];
        union { ushort us[8]; uint4 v; } pk;
        pk.us[0] = f2bf(a.x); pk.us[1] = f2bf(a.y); pk.us[2] = f2bf(a.z); pk.us[3] = f2bf(a.w);
        pk.us[4] = f2bf(b.x); pk.us[5] = f2bf(b.y); pk.us[6] = f2bf(b.z); pk.us[7] = f2bf(b.w);
        *(uint4*)&xb[i] = pk.v;
        return;
    }
    const float* w; ushort* wT; int K, N, n0, k0;
    if (blk < 1216) { const int s = blk - 1024; w = w_qkv; wT = wqkvT; K = 512; N = 1536; n0 = (s % 24) * 64; k0 = (s / 24) * 64; }
    else            { const int s = blk - 1216; w = w_out; wT = woutT; K = 512; N = 512;  n0 = (s % 8) * 64;  k0 = (s / 8) * 64; }
#pragma unroll
    for (int i = 0; i < 4; ++i) {
        const int slot = t + i * 256;
        const int r = slot >> 4, c4 = (slot & 15) * 4;
        float4 v = *(const float4*)&w[(size_t)(k0 + r) * N + n0 + c4];
        tile[c4 + 0][r] = f2bf(v.x);
        tile[c4 + 1][r] = f2bf(v.y);
        tile[c4 + 2][r] = f2bf(v.z);
        tile[c4 + 3][r] = f2bf(v.w);
    }
    __syncthreads();
    const int n = t >> 2, kc = (t & 3) * 16;
    union { ushort us[16]; uint4 v[2]; } o;
#pragma unroll
    for (int j = 0; j < 16; ++j) o.us[j] = tile[n][kc + j];
    *(uint4*)&wT[(size_t)(n0 + n) * K + k0 + kc]     = o.v[0];
    *(uint4*)&wT[(size_t)(n0 + n) * K + k0 + kc + 8] = o.v[1];
}

// ---------- QKV GEMM 64x128, global_load_lds staging, + RoPE epilogue ----
__global__ __launch_bounds__(256)
void gemm_qkv_rope(const ushort* __restrict__ xb, const ushort* __restrict__ wT,
                   ushort* __restrict__ qb, ushort* __restrict__ kb,
                   ushort* __restrict__ vtb, const float2* __restrict__ rope_tbl)
{
    __shared__ __align__(16) ushort As[64][64];    // unpadded: DMA target
    __shared__ __align__(16) ushort Bs[128][64];
    const int t = threadIdx.x, lane = t & 63, w = t >> 6;
    const int quad = lane >> 4, l16 = lane & 15;
    const int m0 = blockIdx.y * 64, n0 = blockIdx.x * 128;
    const int mw = (w >> 1) * 32, nw = (w & 1) * 64;
    const int krow = lane >> 3, kcol = (lane & 7) * 8;   // DMA lane mapping
    f32x4 acc[2][4] = {};

    for (int k0 = 0; k0 < 512; k0 += 64) {
        __syncthreads();   // previous tile's readers done
        gld16(&xb[(size_t)(m0 + w * 8 + krow) * 512 + k0 + kcol],        &As[w * 8][0]);
        gld16(&xb[(size_t)(m0 + (w + 4) * 8 + krow) * 512 + k0 + kcol],  &As[(w + 4) * 8][0]);
#pragma unroll
        for (int jj = 0; jj < 4; ++jj) {
            const int j = w * 4 + jj;
            gld16(&wT[(size_t)(n0 + j * 8 + krow) * 512 + k0 + kcol], &Bs[j * 8][0]);
        }
        __syncthreads();   // vmcnt drained -> tiles ready
#pragma unroll
        for (int ks = 0; ks < 2; ++ks) {
            short8 a[2], b[4];
#pragma unroll
            for (int i = 0; i < 2; ++i)
                a[i] = *(const short8*)&As[mw + i * 16 + l16][ks * 32 + quad * 8];
#pragma unroll
            for (int j = 0; j < 4; ++j)
                b[j] = *(const short8*)&Bs[nw + j * 16 + l16][ks * 32 + quad * 8];
#pragma unroll
            for (int i = 0; i < 2; ++i)
#pragma unroll
                for (int j = 0; j < 4; ++j)
                    acc[i][j] = mfma16(a[i], b[j], acc[i][j]);
        }
    }

    const int sec = (n0 + nw) >> 9;   // 0=q 1=k 2=v, wave-uniform
    if (sec == 2) {
#pragma unroll
        for (int i = 0; i < 2; ++i) {
            const int m = m0 + mw + i * 16 + quad * 4;
            const int bidx = m >> 11, n = m & 2047;
#pragma unroll
            for (int j = 0; j < 4; ++j) {
                const int nc = n0 + nw + j * 16 + l16;
                const int d = nc & 63, h = (nc >> 6) & 7;
                ushort4 pk;
                pk.x = f2bf(acc[i][j][0]); pk.y = f2bf(acc[i][j][1]);
                pk.z = f2bf(acc[i][j][2]); pk.w = f2bf(acc[i][j][3]);
                *(ushort4*)&vtb[(((size_t)bidx * 8 + h) * 64 + d) * 2048 + n] = pk;
            }
        }
    } else {
        ushort* dst = (sec == 0) ? qb : kb;
        const float scale = (sec == 0) ? 0.125f : 1.0f;
#pragma unroll
        for (int j = 0; j < 4; ++j) {
            const int nc = n0 + nw + j * 16 + l16;
            const int d = nc & 63, h = (nc >> 6) & 7;
            const float2* tb = rope_tbl + (d >> 1);
#pragma unroll
            for (int i = 0; i < 2; ++i)
#pragma unroll
            for (int r = 0; r < 4; ++r) {
                const int m = m0 + mw + i * 16 + quad * 4 + r;
                const int bidx = m >> 11, n = m & 2047;
                const float2 cs2 = tb[(size_t)n * 32];
                const float vacc = acc[i][j][r];
                const float partner = __shfl_xor(vacc, 1);
                const float rot = (d & 1) ? (vacc * cs2.x + partner * cs2.y)
                                          : (vacc * cs2.x - partner * cs2.y);
                dst[(((size_t)bidx * 8 + h) * 2048 + n) * 64 + d] = f2bf(rot * scale);
            }
        }
    }
}

// ---- flash R7: SINGLE bias load per tile, shared by both batch iters ----
// R6 showed dup bias reads are NOT L1-absorbed (request model: R3 512MB->76us,
// R6 548MB->79.6us, both == bytes/6.9TB/s). R7 loads each bias tile into regs
// ONCE and uses it for the b0 AND b1 iteration of that tile.
//  - bias slots keyed by TILE parity: pair T reads slot T&1; the opposite
//    slot is refilled with tile T+1 two iters ahead (its last read was >=2
//    iters ago -> no hazard; register WAR ordered by compiler).
//  - uniform per-iter VMEM issue: stage[4] every iter, bias[16] every EVEN
//    iter. Ledger: ops newer than stage(it) at top of iter it = 4+16 = 20
//    => vmcnt(20) every iter (0 on the last). Prologue = Q[4], st(it0)[4],
//    st(it1)[4], bias_t0[16] -> iter0's W(20) drains exactly st(it0).
//  - frame otherwise R6's: QBLK=64, 256thr, tri-buffered K/V via gld16,
//    kv-split x2 (512 blocks = 2/CU, LDS 58KB), fp32 partials + combine.
//  - requests: K/V 256 + bias 128(unique) + partials 36 = 420MB -> ~61us.
// NO launch_bounds min-waves arg (R5 lesson).
__global__ __launch_bounds__(256)
void flash_attn_mfma(const ushort* __restrict__ qb, const ushort* __restrict__ kb,
                     const ushort* __restrict__ vtb, const float* __restrict__ bias,
                     float* __restrict__ opart, float* __restrict__ lpart)
{
    __shared__ __align__(16) ushort Ks[3][64][64];   // 24KB, swizzled, DMA tgt
    __shared__ __align__(16) ushort Vt[3][64][64];   // 24KB, [dim][seq], swz
    __shared__ __align__(16) ushort Ps[4][16][72];   // 9KB
    const int t = threadIdx.x, lane = t & 63, w = t >> 6;   // w in [0,4)
    const int quad = lane >> 4, l16 = lane & 15;
    const int q0 = blockIdx.x * 64, h = blockIdx.y, ksp = blockIdx.z;
    const int kv0 = ksp * 1024;                      // this split's kv range
    const ushort* Q0  = qb  + (size_t)h * SEQ * HDIM;
    const ushort* Q1  = qb  + (size_t)(NHEAD + h) * SEQ * HDIM;
    const ushort* Kp0 = kb  + (size_t)h * SEQ * HDIM;
    const ushort* Kp1 = kb  + (size_t)(NHEAD + h) * SEQ * HDIM;
    const ushort* VT0 = vtb + (size_t)h * HDIM * SEQ;
    const ushort* VT1 = vtb + (size_t)(NHEAD + h) * HDIM * SEQ;
    const float*  Bp  = bias + ((size_t)h * SEQ + q0 + w * 16) * SEQ + kv0;

    f32x4 oacc0[4] = {}, oacc1[4] = {};
    float lsum0[4] = {}, lsum1[4] = {};
    const int krow = lane >> 3;                       // K/V DMA row-in-8
    const int kcolsw = ((lane & 7) ^ krow) * 8;       // swizzled source chunk
    const int sw = l16 & 7;
    const int c0 = (quad ^ sw) * 8;                   // swizzled read col ks=0
    const int c1 = ((quad + 4) ^ sw) * 8;             // ks=1

    // Q for both batches, pinned BEFORE any staging (vmcnt ledger: 4 loads)
    short8 qf0[2], qf1[2];
    qf0[0] = *(const short8*)&Q0[(size_t)(q0 + w * 16 + l16) * HDIM + quad * 8];
    qf0[1] = *(const short8*)&Q0[(size_t)(q0 + w * 16 + l16) * HDIM + 32 + quad * 8];
    qf1[0] = *(const short8*)&Q1[(size_t)(q0 + w * 16 + l16) * HDIM + quad * 8];
    qf1[1] = *(const short8*)&Q1[(size_t)(q0 + w * 16 + l16) * HDIM + 32 + quad * 8];
    asm volatile("" ::: "memory");

    float bs0[16], bs1[16];   // bias slots, keyed by TILE parity

    // stage K/V tile TILE (batch via KPp/VTp) into LDS buffer BUF: 4 gld16
#define FA_STAGE(BUF, TILE, KPp, VTp)                                               \
    {                                                                               \
        const int k2_ = kv0 + (TILE) * 64;                                          \
        gld16(&KPp[(size_t)(k2_ + w * 8 + krow) * HDIM + kcolsw],       &Ks[BUF][w * 8][0]);       \
        gld16(&KPp[(size_t)(k2_ + (w + 4) * 8 + krow) * HDIM + kcolsw], &Ks[BUF][(w + 4) * 8][0]); \
        gld16(&VTp[(size_t)(w * 8 + krow) * SEQ + k2_ + kcolsw],        &Vt[BUF][w * 8][0]);       \
        gld16(&VTp[(size_t)((w + 4) * 8 + krow) * SEQ + k2_ + kcolsw],  &Vt[BUF][(w + 4) * 8][0]); \
    }

    // bias tile TILE -> 16 fp32 regs (row quad*4+r, col s*16+l16)
#define FA_BIAS(BREG, TILE)                                                         \
    {                                                                               \
        const int k2_ = (TILE) * 64;                                                \
        _Pragma("unroll")                                                           \
        for (int r = 0; r < 4; ++r)                                                 \
            _Pragma("unroll")                                                       \
            for (int s = 0; s < 4; ++s)                                             \
                BREG[r * 4 + s] = Bp[(size_t)(quad * 4 + r) * SEQ + k2_ + s * 16 + l16]; \
    }

    // one iteration. BREG: slot read by this tile. If DO_B: refill BR2 with
    // bias tile BT2 (the OTHER slot; register WAR ordered by compiler).
#define FA_BODY(IT, QF, OACC, LSUM, BREG, DO_B, BR2, BT2, KPp, VTp, DO_KV, WCNT)    \
    {                                                                               \
        asm volatile("s_waitcnt vmcnt(" #WCNT ")" ::: "memory");                    \
        __builtin_amdgcn_s_barrier();                                               \
        const int cb_ = (IT) % 3;                                                   \
        if (DO_KV) {                                                                \
            FA_STAGE(((IT) + 2) % 3, ((IT) + 2) >> 1, KPp, VTp);                    \
            asm volatile("" ::: "memory");   /* pin: stage before bias */           \
        }                                                                           \
        f32x4 sacc[4] = {};                                                         \
        __builtin_amdgcn_s_setprio(1);                                              \
        _Pragma("unroll")                                                           \
        for (int s = 0; s < 4; ++s) {                                               \
            short8 kf0 = *(const short8*)&Ks[cb_][s * 16 + l16][c0];                \
            sacc[s] = mfma16(QF[0], kf0, sacc[s]);                                  \
            short8 kf1 = *(const short8*)&Ks[cb_][s * 16 + l16][c1];                \
            sacc[s] = mfma16(QF[1], kf1, sacc[s]);                                  \
        }                                                                           \
        __builtin_amdgcn_s_setprio(0);                                              \
        _Pragma("unroll")                                                           \
        for (int r = 0; r < 4; ++r)                                                 \
            _Pragma("unroll")                                                       \
            for (int s = 0; s < 4; ++s) {                                           \
                const float p = __expf(sacc[s][r] + BREG[r * 4 + s]);               \
                LSUM[r] += p;                                                       \
                Ps[w][quad * 4 + r][s * 16 + l16] = f2bf(p);                        \
            }                                                                       \
        if (DO_B) FA_BIAS(BR2, BT2);                                                \
        asm volatile("" ::: "memory");   /* Ps writes before Ps reads */            \
        __builtin_amdgcn_s_setprio(1);                                              \
        _Pragma("unroll")                                                           \
        for (int ks2 = 0; ks2 < 2; ++ks2) {                                         \
            short8 pf = *(const short8*)&Ps[w][l16][ks2 * 32 + quad * 8];           \
            const int cc_ = ks2 ? c1 : c0;                                          \
            _Pragma("unroll")                                                       \
            for (int s = 0; s < 4; ++s) {                                           \
                short8 vf = *(const short8*)&Vt[cb_][s * 16 + l16][cc_];            \
                OACC[s] = mfma16(pf, vf, OACC[s]);                                  \
            }                                                                       \
        }                                                                           \
        __builtin_amdgcn_s_setprio(0);                                              \
    }

    // prologue: stage it0 (tile0,b0) + it1 (tile0,b1), bias tile0 -> slot0
    FA_STAGE(0, 0, Kp0, VT0);
    asm volatile("" ::: "memory");
    FA_STAGE(1, 0, Kp1, VT1);
    asm volatile("" ::: "memory");
    FA_BIAS(bs0, 0);
    asm volatile("" ::: "memory");

    // U covers tiles 2U (slot0) and 2U+1 (slot1); 4 iters each.
    // Refills: slot1<-tile(2U+1) at iter 4U; slot0<-tile(2U+2) at iter 4U+2.
    for (int U = 0; U < 7; ++U) {
        FA_BODY(4 * U + 0, qf0, oacc0, lsum0, bs0, 1, bs1, 2 * U + 1, Kp0, VT0, 1, 20);
        FA_BODY(4 * U + 1, qf1, oacc1, lsum1, bs0, 0, bs1, 0,         Kp1, VT1, 1, 20);
        FA_BODY(4 * U + 2, qf0, oacc0, lsum0, bs1, 1, bs0, 2 * U + 2, Kp0, VT0, 1, 20);
        FA_BODY(4 * U + 3, qf1, oacc1, lsum1, bs1, 0, bs0, 0,         Kp1, VT1, 1, 20);
    }
    // tail: tiles 14 (slot0, refill slot1<-15) and 15 (slot1, no stage)
    FA_BODY(28, qf0, oacc0, lsum0, bs0, 1, bs1, 15, Kp0, VT0, 1, 20);
    FA_BODY(29, qf1, oacc1, lsum1, bs0, 0, bs1, 0,  Kp1, VT1, 1, 20);
    FA_BODY(30, qf0, oacc0, lsum0, bs1, 0, bs0, 0,  Kp0, VT0, 0, 20);
    FA_BODY(31, qf1, oacc1, lsum1, bs1, 0, bs0, 0,  Kp1, VT1, 0, 0);

#undef FA_BODY
#undef FA_BIAS
#undef FA_STAGE

    // epilogue: partial row-sums + fp32 partial O for this kv-split
    const size_t obase = (size_t)ksp * (4096 * 512);
#define FA_EPI(OACC, LSUM, BB)                                                      \
    {                                                                               \
        _Pragma("unroll")                                                           \
        for (int r = 0; r < 4; ++r) {                                               \
            float rs = LSUM[r];                                                     \
            rs += __shfl_xor(rs, 1, 16);                                            \
            rs += __shfl_xor(rs, 2, 16);                                            \
            rs += __shfl_xor(rs, 4, 16);                                            \
            rs += __shfl_xor(rs, 8, 16);                                            \
            const int q = q0 + w * 16 + quad * 4 + r;                               \
            const size_t m = (size_t)(BB) * SEQ + q;                                \
            if (l16 == 0)                                                           \
                lpart[(((size_t)ksp * NHEAD + h) * 2 + (BB)) * SEQ + q] = rs;       \
            _Pragma("unroll")                                                       \
            for (int s = 0; s < 4; ++s)                                             \
                opart[obase + m * 512 + h * 64 + s * 16 + l16] = OACC[s][r];        \
        }                                                                           \
    }
    FA_EPI(oacc0, lsum0, 0);
    FA_EPI(oacc1, lsum1, 1);
#undef FA_EPI
}

// ---- combine kv-split partials -> normalized bf16 attnb [4096][512] -----
__global__ __launch_bounds__(256)
void combine_o(const float* __restrict__ opart, const float* __restrict__ lpart,
               ushort* __restrict__ ob)
{
    const int idx = blockIdx.x * 256 + threadIdx.x;   // 0..524287
    const int m = idx >> 7;                           // row 0..4095
    const int c4 = (idx & 127) * 4;                   // col 0,4,..508
    const int h = c4 >> 6, bb = m >> 11, q = m & 2047;
    float4 acc = make_float4(0.f, 0.f, 0.f, 0.f);
    float l = 0.f;
#pragma unroll
    for (int s = 0; s < 2; ++s) {
        const float4 p = *(const float4*)&opart[(size_t)s * (4096 * 512) + (size_t)m * 512 + c4];
        acc.x += p.x; acc.y += p.y; acc.z += p.z; acc.w += p.w;
        l += lpart[(((size_t)s * NHEAD + h) * 2 + bb) * SEQ + q];
    }
    const float inv = 1.0f / l;
    ushort4 o;
    o.x = f2bf(acc.x * inv); o.y = f2bf(acc.y * inv);
    o.z = f2bf(acc.z * inv); o.w = f2bf(acc.w * inv);
    *(ushort4*)&ob[(size_t)m * 512 + c4] = o;
}

// ---------- out GEMM 64x64, global_load_lds staging ----------------------
__global__ __launch_bounds__(256)
void gemm_out(const ushort* __restrict__ Ab, const ushort* __restrict__ wT,
              float* __restrict__ C)
{
    __shared__ __align__(16) ushort As[64][64];
    __shared__ __align__(16) ushort Bs[64][64];
    const int t = threadIdx.x, lane = t & 63, w = t >> 6;
    const int quad = lane >> 4, l16 = lane & 15;
    const int m0 = blockIdx.y * 64, n0 = blockIdx.x * 64;
    const int mw = (w >> 1) * 32, nw = (w & 1) * 32;
    const int krow = lane >> 3, kcol = (lane & 7) * 8;
    f32x4 acc[2][2] = {};

    for (int k0 = 0; k0 < 512; k0 += 64) {
        __syncthreads();
        gld16(&Ab[(size_t)(m0 + w * 8 + krow) * 512 + k0 + kcol],       &As[w * 8][0]);
        gld16(&Ab[(size_t)(m0 + (w + 4) * 8 + krow) * 512 + k0 + kcol], &As[(w + 4) * 8][0]);
        gld16(&wT[(size_t)(n0 + w * 8 + krow) * 512 + k0 + kcol],       &Bs[w * 8][0]);
        gld16(&wT[(size_t)(n0 + (w + 4) * 8 + krow) * 512 + k0 + kcol], &Bs[(w + 4) * 8][0]);
        __syncthreads();
#pragma unroll
        for (int ks = 0; ks < 2; ++ks) {
            short8 a[2], b[2];
#pragma unroll
            for (int i = 0; i < 2; ++i)
                a[i] = *(const short8*)&As[mw + i * 16 + l16][ks * 32 + quad * 8];
#pragma unroll
            for (int j = 0; j < 2; ++j)
                b[j] = *(const short8*)&Bs[nw + j * 16 + l16][ks * 32 + quad * 8];
#pragma unroll
            for (int i = 0; i < 2; ++i)
#pragma unroll
                for (int j = 0; j < 2; ++j)
                    acc[i][j] = mfma16(a[i], b[j], acc[i][j]);
        }
    }
#pragma unroll
    for (int i = 0; i < 2; ++i)
#pragma unroll
    for (int r = 0; r < 4; ++r) {
        const int m = m0 + mw + i * 16 + quad * 4 + r;
#pragma unroll
        for (int j = 0; j < 2; ++j)
            C[(size_t)m * 512 + n0 + nw + j * 16 + l16] = acc[i][j][r];
    }
}

extern "C" void kernel_launch(void* const* d_in, const int* in_sizes, int n_in,
                              void* d_out, int out_size, void* d_ws, size_t ws_size,
                              hipStream_t stream)
{
    const float* x        = (const float*)d_in[0];
    const float* pos_bias = (const float*)d_in[1];
    const float* w_qkv    = (const float*)d_in[2];
    const float* w_out    = (const float*)d_in[3];
    float* out = (float*)d_out;

    char* ws = (char*)d_ws;
    ushort* xb     = (ushort*)(ws);                            // 4 MB
    ushort* wqkvT  = (ushort*)(ws + 4194304);                  // 1.5 MB
    ushort* woutT  = (ushort*)(ws + 5767168);                  // 0.5 MB
    ushort* qb     = (ushort*)(ws + 6291456);                  // 4 MB
    ushort* kb     = (ushort*)(ws + 10485760);                 // 4 MB
    ushort* vtb    = (ushort*)(ws + 14680064);                 // 4 MB (V^T)
    ushort* attnb  = (ushort*)(ws + 18874368);                 // 4 MB
    float2* ropetb = (float2*)(ws + 23068672);                 // 512 KB
    float*  opart  = (float*)(ws + 25165824);                  // 16 MB (2 splits)
    float*  lpart  = (float*)(ws + 41943040);                  // 512 KB

    prep<<<1296, 256, 0, stream>>>(x, w_qkv, w_out, xb, wqkvT, woutT, ropetb);
    gemm_qkv_rope<<<dim3(12, 64), 256, 0, stream>>>(xb, wqkvT, qb, kb, vtb, ropetb);
    flash_attn_mfma<<<dim3(SEQ / 64, NHEAD, 2), 256, 0, stream>>>(qb, kb, vtb, pos_bias, opart, lpart);
    combine_o<<<2048, 256, 0, stream>>>(opart, lpart, attnb);
    gemm_out<<<dim3(8, 64), 256, 0, stream>>>(attnb, woutT, out);
}

// Round 8
// 255.239 us; speedup vs baseline: 1.4239x; 1.0200x over previous
//
#include <hip/hip_runtime.h>
#include <math.h>

#define SEQ 2048
#define NHEAD 8
#define HDIM 64
#define BATCH 2

typedef __attribute__((ext_vector_type(8))) short short8;
typedef __attribute__((ext_vector_type(4))) float f32x4;

__device__ __forceinline__ ushort f2bf(float f) {
    union { float f; unsigned u; } v; v.f = f;
    unsigned r = v.u + 0x7FFFu + ((v.u >> 16) & 1u);   // RNE
    return (ushort)(r >> 16);
}

__device__ __forceinline__ f32x4 mfma16(short8 a, short8 b, f32x4 c) {
    return __builtin_amdgcn_mfma_f32_16x16x32_bf16(a, b, c, 0, 0, 0);
}

// global->LDS DMA, 16B per lane; ldsp must be wave-uniform (lane i lands at
// ldsp + i*16).
__device__ __forceinline__ void gld16(const void* g, void* l) {
    __builtin_amdgcn_global_load_lds(
        (const __attribute__((address_space(1))) unsigned int*)g,
        (__attribute__((address_space(3))) unsigned int*)l, 16, 0, 0);
}

// ------- fused prep: pack x + transpose both weights + RoPE table --------
__global__ __launch_bounds__(256)
void prep(const float* __restrict__ x, const float* __restrict__ w_qkv,
          const float* __restrict__ w_out, ushort* __restrict__ xb,
          ushort* __restrict__ wqkvT, ushort* __restrict__ woutT,
          float2* __restrict__ rope_tbl)
{
    __shared__ ushort tile[64][66];
    const int blk = blockIdx.x, t = threadIdx.x;
    if (blk >= 1280) {                      // RoPE cos/sin table [2048][32]
        const int idx = (blk - 1280) * 256 + t;      // 0..4095
        const int n = idx >> 1, fbase = (idx & 1) * 16;
#pragma unroll
        for (int f = 0; f < 16; ++f) {
            const float inv = __expf(-(float)(fbase + f) * (9.2103403719761836f / 32.0f));
            float sn, cs;
            __sincosf((float)n * inv, &sn, &cs);
            rope_tbl[(size_t)n * 32 + fbase + f] = make_float2(cs, sn);
        }
        return;
    }
    if (blk < 1024) {                       // pack x -> bf16
        const int i = (blk * 256 + t) * 8;
        float4 a = *(const float4*)&x[i];
        float4 b = *(const float4*)&x[i + 4];
        union { ushort us[8]; uint4 v; } pk;
        pk.us[0] = f2bf(a.x); pk.us[1] = f2bf(a.y); pk.us[2] = f2bf(a.z); pk.us[3] = f2bf(a.w);
        pk.us[4] = f2bf(b.x); pk.us[5] = f2bf(b.y); pk.us[6] = f2bf(b.z); pk.us[7] = f2bf(b.w);
        *(uint4*)&xb[i] = pk.v;
        return;
    }
    const float* w; ushort* wT; int K, N, n0, k0;
    if (blk < 1216) { const int s = blk - 1024; w = w_qkv; wT = wqkvT; K = 512; N = 1536; n0 = (s % 24) * 64; k0 = (s / 24) * 64; }
    else            { const int s = blk - 1216; w = w_out; wT = woutT; K = 512; N = 512;  n0 = (s % 8) * 64;  k0 = (s / 8) * 64; }
#pragma unroll
    for (int i = 0; i < 4; ++i) {
        const int slot = t + i * 256;
        const int r = slot >> 4, c4 = (slot & 15) * 4;
        float4 v = *(const float4*)&w[(size_t)(k0 + r) * N + n0 + c4];
        tile[c4 + 0][r] = f2bf(v.x);
        tile[c4 + 1][r] = f2bf(v.y);
        tile[c4 + 2][r] = f2bf(v.z);
        tile[c4 + 3][r] = f2bf(v.w);
    }
    __syncthreads();
    const int n = t >> 2, kc = (t & 3) * 16;
    union { ushort us[16]; uint4 v[2]; } o;
#pragma unroll
    for (int j = 0; j < 16; ++j) o.us[j] = tile[n][kc + j];
    *(uint4*)&wT[(size_t)(n0 + n) * K + k0 + kc]     = o.v[0];
    *(uint4*)&wT[(size_t)(n0 + n) * K + k0 + kc + 8] = o.v[1];
}

// ---------- QKV GEMM 64x128, global_load_lds staging, + RoPE epilogue ----
__global__ __launch_bounds__(256)
void gemm_qkv_rope(const ushort* __restrict__ xb, const ushort* __restrict__ wT,
                   ushort* __restrict__ qb, ushort* __restrict__ kb,
                   ushort* __restrict__ vtb, const float2* __restrict__ rope_tbl)
{
    __shared__ __align__(16) ushort As[64][64];    // unpadded: DMA target
    __shared__ __align__(16) ushort Bs[128][64];
    const int t = threadIdx.x, lane = t & 63, w = t >> 6;
    const int quad = lane >> 4, l16 = lane & 15;
    const int m0 = blockIdx.y * 64, n0 = blockIdx.x * 128;
    const int mw = (w >> 1) * 32, nw = (w & 1) * 64;
    const int krow = lane >> 3, kcol = (lane & 7) * 8;   // DMA lane mapping
    f32x4 acc[2][4] = {};

    for (int k0 = 0; k0 < 512; k0 += 64) {
        __syncthreads();   // previous tile's readers done
        gld16(&xb[(size_t)(m0 + w * 8 + krow) * 512 + k0 + kcol],        &As[w * 8][0]);
        gld16(&xb[(size_t)(m0 + (w + 4) * 8 + krow) * 512 + k0 + kcol],  &As[(w + 4) * 8][0]);
#pragma unroll
        for (int jj = 0; jj < 4; ++jj) {
            const int j = w * 4 + jj;
            gld16(&wT[(size_t)(n0 + j * 8 + krow) * 512 + k0 + kcol], &Bs[j * 8][0]);
        }
        __syncthreads();   // vmcnt drained -> tiles ready
#pragma unroll
        for (int ks = 0; ks < 2; ++ks) {
            short8 a[2], b[4];
#pragma unroll
            for (int i = 0; i < 2; ++i)
                a[i] = *(const short8*)&As[mw + i * 16 + l16][ks * 32 + quad * 8];
#pragma unroll
            for (int j = 0; j < 4; ++j)
                b[j] = *(const short8*)&Bs[nw + j * 16 + l16][ks * 32 + quad * 8];
#pragma unroll
            for (int i = 0; i < 2; ++i)
#pragma unroll
                for (int j = 0; j < 4; ++j)
                    acc[i][j] = mfma16(a[i], b[j], acc[i][j]);
        }
    }

    const int sec = (n0 + nw) >> 9;   // 0=q 1=k 2=v, wave-uniform
    if (sec == 2) {
#pragma unroll
        for (int i = 0; i < 2; ++i) {
            const int m = m0 + mw + i * 16 + quad * 4;
            const int bidx = m >> 11, n = m & 2047;
#pragma unroll
            for (int j = 0; j < 4; ++j) {
                const int nc = n0 + nw + j * 16 + l16;
                const int d = nc & 63, h = (nc >> 6) & 7;
                ushort4 pk;
                pk.x = f2bf(acc[i][j][0]); pk.y = f2bf(acc[i][j][1]);
                pk.z = f2bf(acc[i][j][2]); pk.w = f2bf(acc[i][j][3]);
                *(ushort4*)&vtb[(((size_t)bidx * 8 + h) * 64 + d) * 2048 + n] = pk;
            }
        }
    } else {
        ushort* dst = (sec == 0) ? qb : kb;
        const float scale = (sec == 0) ? 0.125f : 1.0f;
#pragma unroll
        for (int j = 0; j < 4; ++j) {
            const int nc = n0 + nw + j * 16 + l16;
            const int d = nc & 63, h = (nc >> 6) & 7;
            const float2* tb = rope_tbl + (d >> 1);
#pragma unroll
            for (int i = 0; i < 2; ++i)
#pragma unroll
            for (int r = 0; r < 4; ++r) {
                const int m = m0 + mw + i * 16 + quad * 4 + r;
                const int bidx = m >> 11, n = m & 2047;
                const float2 cs2 = tb[(size_t)n * 32];
                const float vacc = acc[i][j][r];
                const float partner = __shfl_xor(vacc, 1);
                const float rot = (d & 1) ? (vacc * cs2.x + partner * cs2.y)
                                          : (vacc * cs2.x - partner * cs2.y);
                dst[(((size_t)bidx * 8 + h) * 2048 + n) * 64 + d] = f2bf(rot * scale);
            }
        }
    }
}

// ---- flash attention (R3 schedule, best measured: ~76us, total 251us) ---
// reg-bias (16 fp32/thread, 2 slots, issued 2 iters ahead), triple-buffered
// K/V via gld16 (2-iter lookahead), counted vmcnt W(36)/W(16), ONE barrier
// per iter, setprio around MFMA, direct bf16 epilogue. QBLK=64, 256 thr,
// grid 32x8x2 = 512 blocks = 2 blocks/CU (LDS 58KB).
// Kept verbatim: R5-R7's byte-reduction variants (dup-bias partials, shared
// bias slots) all regressed despite lower FETCH_SIZE -- this schedule is the
// empirical optimum of 8 tested variants.
__global__ __launch_bounds__(256)
void flash_attn_mfma(const ushort* __restrict__ qb, const ushort* __restrict__ kb,
                     const ushort* __restrict__ vtb, const float* __restrict__ bias,
                     ushort* __restrict__ ob)
{
    __shared__ __align__(16) ushort Ks[3][64][64];   // 24KB, swizzled, DMA tgt
    __shared__ __align__(16) ushort Vt[3][64][64];   // 24KB, [dim][seq], swz
    __shared__ __align__(16) ushort Ps[4][16][72];   // 9KB
    const int t = threadIdx.x, lane = t & 63, w = t >> 6;   // w in [0,4)
    const int quad = lane >> 4, l16 = lane & 15;
    const int q0 = blockIdx.x * 64, h = blockIdx.y, b = blockIdx.z;
    const size_t bh = (size_t)(b * NHEAD + h);
    const ushort* Q  = qb  + bh * SEQ * HDIM;
    const ushort* Kp = kb  + bh * SEQ * HDIM;
    const ushort* VT = vtb + bh * HDIM * SEQ;
    const float*  Bp = bias + ((size_t)h * SEQ + q0 + w * 16) * SEQ;  // wave's rows

    f32x4 oacc[4] = {};
    float lsum[4] = {};
    const int krow = lane >> 3;                       // K/V DMA row-in-8
    const int kcolsw = ((lane & 7) ^ krow) * 8;       // swizzled source chunk

    // swizzled read columns: logical chunk (ks*4+quad) at row with row&7==l16&7
    const int sw = l16 & 7;
    const int c0 = (quad ^ sw) * 8;           // ks=0
    const int c1 = ((quad + 4) ^ sw) * 8;     // ks=1

    short8 qf[2];
    qf[0] = *(const short8*)&Q[(size_t)(q0 + w * 16 + l16) * HDIM + quad * 8];
    qf[1] = *(const short8*)&Q[(size_t)(q0 + w * 16 + l16) * HDIM + 32 + quad * 8];
    asm volatile("" ::: "memory");   // Q loads issued before staging groups

    float b0[16], b1[16];

    // stage K/V tile IT_ into LDS buffer BUF (4 gld16 / thread, 4 waves)
#define FA_STAGE(BUF, IT_)                                                          \
    {                                                                               \
        const int k2_ = (IT_) * 64;                                                 \
        gld16(&Kp[(size_t)(k2_ + w * 8 + krow) * HDIM + kcolsw],       &Ks[BUF][w * 8][0]);       \
        gld16(&Kp[(size_t)(k2_ + (w + 4) * 8 + krow) * HDIM + kcolsw], &Ks[BUF][(w + 4) * 8][0]); \
        gld16(&VT[(size_t)(w * 8 + krow) * SEQ + k2_ + kcolsw],        &Vt[BUF][w * 8][0]);       \
        gld16(&VT[(size_t)((w + 4) * 8 + krow) * SEQ + k2_ + kcolsw],  &Vt[BUF][(w + 4) * 8][0]); \
    }

    // bias tile IT_ -> 16 fp32 registers (row quad*4+r, col s*16+l16)
#define FA_BIAS(BREG, IT_)                                                          \
    {                                                                               \
        const int k2_ = (IT_) * 64;                                                 \
        _Pragma("unroll")                                                           \
        for (int r = 0; r < 4; ++r)                                                 \
            _Pragma("unroll")                                                       \
            for (int s = 0; s < 4; ++s)                                             \
                BREG[r * 4 + s] = Bp[(size_t)(quad * 4 + r) * SEQ + k2_ + s * 16 + l16]; \
    }

    // one iteration. WCNT: vmcnt immediate at top. REFILL: issue it+2 loads.
#define FA_BODY(IT, BCUR, REFILL, WCNT)                                             \
    {                                                                               \
        asm volatile("s_waitcnt vmcnt(" #WCNT ")" ::: "memory");                    \
        __builtin_amdgcn_s_barrier();                                               \
        const int cb_ = (IT) % 3;                                                   \
        if (REFILL) {                                                               \
            FA_STAGE(((IT) + 2) % 3, (IT) + 2);                                     \
            asm volatile("" ::: "memory");   /* pin: stage before bias */           \
        }                                                                           \
        f32x4 sacc[4] = {};                                                         \
        __builtin_amdgcn_s_setprio(1);                                              \
        _Pragma("unroll")                                                           \
        for (int s = 0; s < 4; ++s) {                                               \
            short8 kf0 = *(const short8*)&Ks[cb_][s * 16 + l16][c0];                \
            sacc[s] = mfma16(qf[0], kf0, sacc[s]);                                  \
            short8 kf1 = *(const short8*)&Ks[cb_][s * 16 + l16][c1];                \
            sacc[s] = mfma16(qf[1], kf1, sacc[s]);                                  \
        }                                                                           \
        __builtin_amdgcn_s_setprio(0);                                              \
        _Pragma("unroll")                                                           \
        for (int r = 0; r < 4; ++r)                                                 \
            _Pragma("unroll")                                                       \
            for (int s = 0; s < 4; ++s) {                                           \
                const float p = __expf(sacc[s][r] + BCUR[r * 4 + s]);               \
                lsum[r] += p;                                                       \
                Ps[w][quad * 4 + r][s * 16 + l16] = f2bf(p);                        \
            }                                                                       \
        if (REFILL) FA_BIAS(BCUR, (IT) + 2);                                        \
        asm volatile("" ::: "memory");   /* Ps writes before Ps reads */            \
        __builtin_amdgcn_s_setprio(1);                                              \
        _Pragma("unroll")                                                           \
        for (int ks = 0; ks < 2; ++ks) {                                            \
            short8 pf = *(const short8*)&Ps[w][l16][ks * 32 + quad * 8];            \
            const int cc_ = ks ? c1 : c0;                                           \
            _Pragma("unroll")                                                       \
            for (int s = 0; s < 4; ++s) {                                           \
                short8 vf = *(const short8*)&Vt[cb_][s * 16 + l16][cc_];            \
                oacc[s] = mfma16(pf, vf, oacc[s]);                                  \
            }                                                                       \
        }                                                                           \
        __builtin_amdgcn_s_setprio(0);                                              \
    }

    // prologue: group(0) then group(1), order pinned
    FA_STAGE(0, 0);
    asm volatile("" ::: "memory");
    FA_BIAS(b0, 0);
    asm volatile("" ::: "memory");
    FA_STAGE(1, 1);
    asm volatile("" ::: "memory");
    FA_BIAS(b1, 1);

    for (int i2 = 0; i2 < 15; ++i2) {
        FA_BODY(2 * i2,     b0, 1, 36);
        FA_BODY(2 * i2 + 1, b1, 1, 36);
    }
    FA_BODY(30, b0, 0, 36);
    FA_BODY(31, b1, 0, 16);

#undef FA_BODY
#undef FA_BIAS
#undef FA_STAGE

    // epilogue: cross-lane row-sum, normalize, write attnb [4096][512]
#pragma unroll
    for (int r = 0; r < 4; ++r) {
        float rs = lsum[r];
        rs += __shfl_xor(rs, 1, 16);
        rs += __shfl_xor(rs, 2, 16);
        rs += __shfl_xor(rs, 4, 16);
        rs += __shfl_xor(rs, 8, 16);
        const float invl = 1.0f / rs;
        const size_t m = (size_t)b * SEQ + q0 + w * 16 + quad * 4 + r;
#pragma unroll
        for (int s = 0; s < 4; ++s)
            ob[m * 512 + h * HDIM + s * 16 + l16] = f2bf(oacc[s][r] * invl);
    }
}

// ---------- out GEMM 64x64, global_load_lds staging ----------------------
__global__ __launch_bounds__(256)
void gemm_out(const ushort* __restrict__ Ab, const ushort* __restrict__ wT,
              float* __restrict__ C)
{
    __shared__ __align__(16) ushort As[64][64];
    __shared__ __align__(16) ushort Bs[64][64];
    const int t = threadIdx.x, lane = t & 63, w = t >> 6;
    const int quad = lane >> 4, l16 = lane & 15;
    const int m0 = blockIdx.y * 64, n0 = blockIdx.x * 64;
    const int mw = (w >> 1) * 32, nw = (w & 1) * 32;
    const int krow = lane >> 3, kcol = (lane & 7) * 8;
    f32x4 acc[2][2] = {};

    for (int k0 = 0; k0 < 512; k0 += 64) {
        __syncthreads();
        gld16(&Ab[(size_t)(m0 + w * 8 + krow) * 512 + k0 + kcol],       &As[w * 8][0]);
        gld16(&Ab[(size_t)(m0 + (w + 4) * 8 + krow) * 512 + k0 + kcol], &As[(w + 4) * 8][0]);
        gld16(&wT[(size_t)(n0 + w * 8 + krow) * 512 + k0 + kcol],       &Bs[w * 8][0]);
        gld16(&wT[(size_t)(n0 + (w + 4) * 8 + krow) * 512 + k0 + kcol], &Bs[(w + 4) * 8][0]);
        __syncthreads();
#pragma unroll
        for (int ks = 0; ks < 2; ++ks) {
            short8 a[2], b[2];
#pragma unroll
            for (int i = 0; i < 2; ++i)
                a[i] = *(const short8*)&As[mw + i * 16 + l16][ks * 32 + quad * 8];
#pragma unroll
            for (int j = 0; j < 2; ++j)
                b[j] = *(const short8*)&Bs[nw + j * 16 + l16][ks * 32 + quad * 8];
#pragma unroll
            for (int i = 0; i < 2; ++i)
#pragma unroll
                for (int j = 0; j < 2; ++j)
                    acc[i][j] = mfma16(a[i], b[j], acc[i][j]);
        }
    }
#pragma unroll
    for (int i = 0; i < 2; ++i)
#pragma unroll
    for (int r = 0; r < 4; ++r) {
        const int m = m0 + mw + i * 16 + quad * 4 + r;
#pragma unroll
        for (int j = 0; j < 2; ++j)
            C[(size_t)m * 512 + n0 + nw + j * 16 + l16] = acc[i][j][r];
    }
}

extern "C" void kernel_launch(void* const* d_in, const int* in_sizes, int n_in,
                              void* d_out, int out_size, void* d_ws, size_t ws_size,
                              hipStream_t stream)
{
    const float* x        = (const float*)d_in[0];
    const float* pos_bias = (const float*)d_in[1];
    const float* w_qkv    = (const float*)d_in[2];
    const float* w_out    = (const float*)d_in[3];
    float* out = (float*)d_out;

    char* ws = (char*)d_ws;
    ushort* xb     = (ushort*)(ws);                            // 4 MB
    ushort* wqkvT  = (ushort*)(ws + 4194304);                  // 1.5 MB
    ushort* woutT  = (ushort*)(ws + 5767168);                  // 0.5 MB
    ushort* qb     = (ushort*)(ws + 6291456);                  // 4 MB
    ushort* kb     = (ushort*)(ws + 10485760);                 // 4 MB
    ushort* vtb    = (ushort*)(ws + 14680064);                 // 4 MB (V^T)
    ushort* attnb  = (ushort*)(ws + 18874368);                 // 4 MB
    float2* ropetb = (float2*)(ws + 23068672);                 // 512 KB

    prep<<<1296, 256, 0, stream>>>(x, w_qkv, w_out, xb, wqkvT, woutT, ropetb);
    gemm_qkv_rope<<<dim3(12, 64), 256, 0, stream>>>(xb, wqkvT, qb, kb, vtb, ropetb);
    flash_attn_mfma<<<dim3(SEQ / 64, NHEAD, BATCH), 256, 0, stream>>>(qb, kb, vtb, pos_bias, attnb);
    gemm_out<<<dim3(8, 64), 256, 0, stream>>>(attnb, woutT, out);
}